// Round 1
// 1202.334 us; speedup vs baseline: 1.0909x; 1.0909x over previous
//
#include <hip/hip_runtime.h>
#include <cstdint>
#include <cstddef>

// ---------------------------------------------------------------------------
// SOARALinear: out = x @ W^T + bias + x @ V^T @ R_V @ diag(S) @ R_U^T @ U^T
// Collapsed:   Wct = W + U @ (R_U diag(S) R_V^T) @ V ;  out = x @ Wct^T + bias
// Large GEMMs: 256x256 tile, BK=64, double-buffered LDS, counted vmcnt(8),
// st-swizzled LDS (bank-conflict-free), setprio around MFMA, XCD swizzle.
// Small GEMMs keep the proven 128x128 kernel.
// ---------------------------------------------------------------------------

typedef __bf16 bf16x8 __attribute__((ext_vector_type(8)));
typedef float floatx4 __attribute__((ext_vector_type(4)));
typedef unsigned short ushortx8 __attribute__((ext_vector_type(8)));

__device__ __forceinline__ unsigned short f2bf(float f) {
    unsigned int u = __builtin_bit_cast(unsigned int, f);
    u += 0x7FFFu + ((u >> 16) & 1u);   // round-to-nearest-even
    return (unsigned short)(u >> 16);
}

__device__ __forceinline__ void gld_lds16(const void* g, void* l) {
    __builtin_amdgcn_global_load_lds(
        (const __attribute__((address_space(1))) void*)g,
        (__attribute__((address_space(3))) void*)l,
        16, 0, 0);
}

// ---------------------------------------------------------------------------
// Butterfly rows: R = C_0 C_1 ... C_9 (d=1024).
// mat 0 -> RVs (R_V with column k scaled by S[k]) bf16 ; mat 1 -> R_U bf16
// ---------------------------------------------------------------------------
__global__ __launch_bounds__(256) void butterfly_rows_kernel(
    const float* __restrict__ thetas_v, const float* __restrict__ thetas_u,
    const float* __restrict__ S,
    unsigned short* __restrict__ RVsb, unsigned short* __restrict__ RUb)
{
    const int d = 1024;
    __shared__ float w[1024];
    const int b   = blockIdx.x;
    const int mat = b >> 10;        // 0: V, 1: U
    const int row = b & 1023;
    const float* th = mat ? thetas_u : thetas_v;
    const int t = threadIdx.x;

    for (int i = t; i < d; i += 256) w[i] = (i == row) ? 1.f : 0.f;
    __syncthreads();

    for (int j = 0; j < 10; ++j) {
        const int sh = 9 - j;
        const int halfm1 = (1 << sh) - 1;
        for (int i = t; i < d / 2; i += 256) {
            const int blk = i >> sh;
            const int off = i & halfm1;
            const int p = (blk << (sh + 1)) + off;
            const int q = p + (halfm1 + 1);
            const float theta = th[j * (d / 2) + i];
            float s, c;
            __sincosf(theta, &s, &c);
            const float wp = w[p], wq = w[q];
            w[p] = c * wp + s * wq;
            w[q] = -s * wp + c * wq;
        }
        __syncthreads();
    }

    if (mat == 0) {
        for (int i = t; i < d; i += 256) RVsb[row * d + i] = f2bf(w[i] * S[i]);
    } else {
        for (int i = t; i < d; i += 256) RUb[row * d + i] = f2bf(w[i]);
    }
}

// ---------------------------------------------------------------------------
__global__ __launch_bounds__(256) void cvt_f32_bf16_x8(
    const float* __restrict__ src, unsigned short* __restrict__ dst)
{
    const size_t i = ((size_t)blockIdx.x * 256 + threadIdx.x) * 8;
    float4 a = *(const float4*)(src + i);
    float4 b = *(const float4*)(src + i + 4);
    ushortx8 o;
    o[0] = f2bf(a.x); o[1] = f2bf(a.y); o[2] = f2bf(a.z); o[3] = f2bf(a.w);
    o[4] = f2bf(b.x); o[5] = f2bf(b.y); o[6] = f2bf(b.z); o[7] = f2bf(b.w);
    *(ushortx8*)(dst + i) = o;
}

// ---------------------------------------------------------------------------
__global__ __launch_bounds__(256) void transpose_to_bf16(
    const float* __restrict__ src, unsigned short* __restrict__ dst,
    int rows, int cols)
{
    __shared__ float tile[32][33];
    const int tx = threadIdx.x & 31, ty = threadIdx.x >> 5;
    const int c0 = blockIdx.x * 32, r0 = blockIdx.y * 32;
    for (int i = 0; i < 32; i += 8)
        tile[ty + i][tx] = src[(size_t)(r0 + ty + i) * cols + c0 + tx];
    __syncthreads();
    for (int i = 0; i < 32; i += 8)
        dst[(size_t)(c0 + ty + i) * rows + r0 + tx] = f2bf(tile[tx][ty + i]);
}

// ---------------------------------------------------------------------------
// Small NT GEMM (kept for the two small rotation GEMMs): 128x128 tile.
// EPI: 2 -> bf16 out
// ---------------------------------------------------------------------------
template <int EPI>
__global__ __launch_bounds__(256) void gemm_nt(
    const unsigned short* __restrict__ A,
    const unsigned short* __restrict__ B,
    float* __restrict__ Cf,
    unsigned short* __restrict__ Cb,
    const float* __restrict__ extra,
    int M, int N, int K)
{
    __shared__ __align__(16) unsigned short As[128 * 32];
    __shared__ __align__(16) unsigned short Bs[128 * 32];

    const int tid  = threadIdx.x;
    const int lane = tid & 63;
    const int wave = tid >> 6;
    const int wm = wave >> 1, wn = wave & 1;

    const int m0 = blockIdx.y * 128;
    const int n0 = blockIdx.x * 128;

    const int srow = wave * 32 + (lane >> 2);
    const int scol = (lane & 3) * 8;

    const unsigned short* gA = A + (size_t)(m0 + srow) * K + scol;
    const unsigned short* gB = B + (size_t)(n0 + srow) * K + scol;
    unsigned short* lA = As + wave * 32 * 32;
    unsigned short* lB = Bs + wave * 32 * 32;

    floatx4 acc[4][4];
#pragma unroll
    for (int i = 0; i < 4; ++i)
#pragma unroll
        for (int j = 0; j < 4; ++j) acc[i][j] = (floatx4)0.f;

    const int ar = lane & 15;
    const int ak = (lane >> 4) * 8;

    for (int kk = 0; kk < K; kk += 32) {
        gld_lds16(gA + kk, lA);
        gld_lds16(gA + kk + (size_t)16 * K, lA + 512);
        gld_lds16(gB + kk, lB);
        gld_lds16(gB + kk + (size_t)16 * K, lB + 512);
        __syncthreads();

        bf16x8 af[4], bfr[4];
#pragma unroll
        for (int tm = 0; tm < 4; ++tm)
            af[tm] = __builtin_bit_cast(bf16x8,
                *(const ushortx8*)&As[(wm * 64 + tm * 16 + ar) * 32 + ak]);
#pragma unroll
        for (int tn = 0; tn < 4; ++tn)
            bfr[tn] = __builtin_bit_cast(bf16x8,
                *(const ushortx8*)&Bs[(wn * 64 + tn * 16 + ar) * 32 + ak]);
#pragma unroll
        for (int tm = 0; tm < 4; ++tm)
#pragma unroll
            for (int tn = 0; tn < 4; ++tn)
                acc[tm][tn] = __builtin_amdgcn_mfma_f32_16x16x32_bf16(
                    af[tm], bfr[tn], acc[tm][tn], 0, 0, 0);
        __syncthreads();
    }

#pragma unroll
    for (int tm = 0; tm < 4; ++tm) {
#pragma unroll
        for (int tn = 0; tn < 4; ++tn) {
#pragma unroll
            for (int r = 0; r < 4; ++r) {
                const int row = m0 + wm * 64 + tm * 16 + (lane >> 4) * 4 + r;
                const int col = n0 + wn * 64 + tn * 16 + (lane & 15);
                const float v = acc[tm][tn][r];
                if (EPI == 1) {
                    Cf[(size_t)row * N + col] = v + extra[col];
                } else if (EPI == 2) {
                    Cb[(size_t)row * N + col] = f2bf(v);
                } else {
                    Cb[(size_t)row * N + col] = f2bf(v + extra[(size_t)row * N + col]);
                }
            }
        }
    }
}

// ---------------------------------------------------------------------------
// Large NT GEMM: 256x256 tile, BK=64, 512 threads (8 waves, 2M x 4N).
// Double-buffered 128 KiB LDS; next K-tile's 8 global_load_lds issued at the
// top of each K-tile, then s_waitcnt vmcnt(8) (counted -- prefetch stays in
// flight across the barrier). 2 barriers per K-tile. LDS XOR-swizzle
// (colbyte ^= (row&7)<<4) applied as: linear LDS dest + inverse-swizzled
// GLOBAL source + swizzled ds_read (rule 21). 4 MFMA phases per K-tile
// (one 64x32 C-quadrant each, 16 MFMA) wrapped in s_setprio.
// EPI 1: f32 out + bias[col] ;  EPI 3: bf16 out + f32 extra[M,N]
// M,N multiples of 256; K multiple of 64.
// ---------------------------------------------------------------------------
template <int EPI>
__global__ __launch_bounds__(512, 2) void gemm256(
    const unsigned short* __restrict__ A,
    const unsigned short* __restrict__ B,
    float* __restrict__ Cf,
    unsigned short* __restrict__ Cb,
    const float* __restrict__ extra,
    int M, int N, int K, int swz_on)
{
    __shared__ __align__(16) unsigned short As[2][256 * 64];
    __shared__ __align__(16) unsigned short Bs[2][256 * 64];

    const int tid  = threadIdx.x;
    const int lane = tid & 63;
    const int wave = tid >> 6;
    const int wm = wave >> 2;      // 0..1  (M half:   128 rows)
    const int wn = wave & 3;       // 0..3  (N quarter: 64 cols)

    int bx = blockIdx.x, by = blockIdx.y;
    if (swz_on) {                  // XCD-aware bijective swizzle (nwg % 8 == 0)
        const int gx  = gridDim.x;
        const int nwg = gx * gridDim.y;
        const int f   = by * gx + bx;
        const int g   = (f & 7) * (nwg >> 3) + (f >> 3);
        bx = g % gx;
        by = g / gx;
    }
    const int m0 = by * 256;
    const int n0 = bx * 256;

    // ---- staging: linear LDS dest, inverse-swizzled global source.
    // thread t covers physical LDS bytes row=slab*64+t/8, colbyte=(t%8)*16
    const int srow  = tid >> 3;                         // 0..63 within a slab
    const int scolb = (tid & 7) << 4;                   // physical col byte
    const int scol  = (scolb ^ ((srow & 7) << 4)) >> 1; // logical col (elems)

    const unsigned short* gA = A + (size_t)(m0 + srow) * K + scol;
    const unsigned short* gB = B + (size_t)(n0 + srow) * K + scol;
    const int ldsoff = wave << 10;                      // wave-uniform base
    const size_t rowstep = (size_t)64 * K;              // 64-row slab stride

    // ---- MFMA fragment read addressing (swizzled)
    const int fr   = lane & 15;
    const int fk2  = ((lane >> 4) & 3) << 4;            // 0/16/32/48 byte
    const int swz  = (fr & 7) << 4;
    const int ca0  = fk2 ^ swz;                         // K-step 0 col byte
    const int ca1  = (64 + fk2) ^ swz;                  // K-step 1 col byte
    const int arow = (wm * 128 + fr) << 7;              // byte row base (A)
    const int brow = (wn * 64 + fr) << 7;               // byte row base (B)

    floatx4 acc[8][4];
#pragma unroll
    for (int i = 0; i < 8; ++i)
#pragma unroll
        for (int j = 0; j < 4; ++j) acc[i][j] = (floatx4)0.f;

    const int nkt = K >> 6;

    // prologue: stage K-tile 0 into buffer 0 (8 loads in flight)
    {
        char* la = (char*)&As[0][0] + ldsoff;
        char* lb = (char*)&Bs[0][0] + ldsoff;
#pragma unroll
        for (int j = 0; j < 4; ++j) gld_lds16(gA + j * rowstep, la + j * 8192);
#pragma unroll
        for (int j = 0; j < 4; ++j) gld_lds16(gB + j * rowstep, lb + j * 8192);
    }

    for (int t = 0; t < nkt; ++t) {
        if (t + 1 < nkt) {
            // issue next K-tile's staging into the other buffer
            const unsigned short* a = gA + (size_t)(t + 1) * 64;
            const unsigned short* b = gB + (size_t)(t + 1) * 64;
            char* la = (char*)&As[(t + 1) & 1][0] + ldsoff;
            char* lb = (char*)&Bs[(t + 1) & 1][0] + ldsoff;
#pragma unroll
            for (int j = 0; j < 4; ++j) gld_lds16(a + j * rowstep, la + j * 8192);
#pragma unroll
            for (int j = 0; j < 4; ++j) gld_lds16(b + j * rowstep, lb + j * 8192);
            __builtin_amdgcn_sched_barrier(0);
            asm volatile("s_waitcnt vmcnt(8)" ::: "memory");  // current tile done
        } else {
            asm volatile("s_waitcnt vmcnt(0)" ::: "memory");  // last tile: drain
        }
        __builtin_amdgcn_s_barrier();
        __builtin_amdgcn_sched_barrier(0);

        const char* ab = (const char*)&As[t & 1][0];
        const char* bb = (const char*)&Bs[t & 1][0];

        bf16x8 af[4][2], b0[2][2], b1[2][2];

        // ---- phase 1: rows mh0, cols nh0
#pragma unroll
        for (int mf = 0; mf < 4; ++mf) {
            af[mf][0] = __builtin_bit_cast(bf16x8, *(const ushortx8*)(ab + arow + (mf << 11) + ca0));
            af[mf][1] = __builtin_bit_cast(bf16x8, *(const ushortx8*)(ab + arow + (mf << 11) + ca1));
        }
#pragma unroll
        for (int nf = 0; nf < 2; ++nf) {
            b0[nf][0] = __builtin_bit_cast(bf16x8, *(const ushortx8*)(bb + brow + (nf << 11) + ca0));
            b0[nf][1] = __builtin_bit_cast(bf16x8, *(const ushortx8*)(bb + brow + (nf << 11) + ca1));
        }
        __builtin_amdgcn_s_setprio(1);
#pragma unroll
        for (int mf = 0; mf < 4; ++mf)
#pragma unroll
            for (int nf = 0; nf < 2; ++nf) {
                acc[mf][nf] = __builtin_amdgcn_mfma_f32_16x16x32_bf16(af[mf][0], b0[nf][0], acc[mf][nf], 0, 0, 0);
                acc[mf][nf] = __builtin_amdgcn_mfma_f32_16x16x32_bf16(af[mf][1], b0[nf][1], acc[mf][nf], 0, 0, 0);
            }
        __builtin_amdgcn_s_setprio(0);

        // ---- phase 2: rows mh0, cols nh1 (reuse af)
#pragma unroll
        for (int nf = 0; nf < 2; ++nf) {
            b1[nf][0] = __builtin_bit_cast(bf16x8, *(const ushortx8*)(bb + brow + 4096 + (nf << 11) + ca0));
            b1[nf][1] = __builtin_bit_cast(bf16x8, *(const ushortx8*)(bb + brow + 4096 + (nf << 11) + ca1));
        }
        __builtin_amdgcn_s_setprio(1);
#pragma unroll
        for (int mf = 0; mf < 4; ++mf)
#pragma unroll
            for (int nf = 0; nf < 2; ++nf) {
                acc[mf][2 + nf] = __builtin_amdgcn_mfma_f32_16x16x32_bf16(af[mf][0], b1[nf][0], acc[mf][2 + nf], 0, 0, 0);
                acc[mf][2 + nf] = __builtin_amdgcn_mfma_f32_16x16x32_bf16(af[mf][1], b1[nf][1], acc[mf][2 + nf], 0, 0, 0);
            }
        __builtin_amdgcn_s_setprio(0);

        // ---- phase 3: rows mh1, cols nh1 (reload af, reuse b1)
#pragma unroll
        for (int mf = 0; mf < 4; ++mf) {
            af[mf][0] = __builtin_bit_cast(bf16x8, *(const ushortx8*)(ab + arow + 8192 + (mf << 11) + ca0));
            af[mf][1] = __builtin_bit_cast(bf16x8, *(const ushortx8*)(ab + arow + 8192 + (mf << 11) + ca1));
        }
        __builtin_amdgcn_s_setprio(1);
#pragma unroll
        for (int mf = 0; mf < 4; ++mf)
#pragma unroll
            for (int nf = 0; nf < 2; ++nf) {
                acc[4 + mf][2 + nf] = __builtin_amdgcn_mfma_f32_16x16x32_bf16(af[mf][0], b1[nf][0], acc[4 + mf][2 + nf], 0, 0, 0);
                acc[4 + mf][2 + nf] = __builtin_amdgcn_mfma_f32_16x16x32_bf16(af[mf][1], b1[nf][1], acc[4 + mf][2 + nf], 0, 0, 0);
            }
        __builtin_amdgcn_s_setprio(0);

        // ---- phase 4: rows mh1, cols nh0 (reload b0)
#pragma unroll
        for (int nf = 0; nf < 2; ++nf) {
            b0[nf][0] = __builtin_bit_cast(bf16x8, *(const ushortx8*)(bb + brow + (nf << 11) + ca0));
            b0[nf][1] = __builtin_bit_cast(bf16x8, *(const ushortx8*)(bb + brow + (nf << 11) + ca1));
        }
        __builtin_amdgcn_s_setprio(1);
#pragma unroll
        for (int mf = 0; mf < 4; ++mf)
#pragma unroll
            for (int nf = 0; nf < 2; ++nf) {
                acc[4 + mf][nf] = __builtin_amdgcn_mfma_f32_16x16x32_bf16(af[mf][0], b0[nf][0], acc[4 + mf][nf], 0, 0, 0);
                acc[4 + mf][nf] = __builtin_amdgcn_mfma_f32_16x16x32_bf16(af[mf][1], b0[nf][1], acc[4 + mf][nf], 0, 0, 0);
            }
        __builtin_amdgcn_s_setprio(0);

        __builtin_amdgcn_sched_barrier(0);
        asm volatile("" ::: "memory");
        __builtin_amdgcn_s_barrier();
    }

    // epilogue: C/D layout col = lane&15, row = (lane>>4)*4 + r
    const int er = wm * 128 + ((lane >> 4) << 2);
    const int ec = wn * 64 + (lane & 15);
#pragma unroll
    for (int mfg = 0; mfg < 8; ++mfg) {
#pragma unroll
        for (int nfg = 0; nfg < 4; ++nfg) {
#pragma unroll
            for (int r = 0; r < 4; ++r) {
                const int row = m0 + er + mfg * 16 + r;
                const int col = n0 + ec + nfg * 16;
                const float v = acc[mfg][nfg][r];
                if (EPI == 1) {
                    Cf[(size_t)row * N + col] = v + extra[col];
                } else {
                    Cb[(size_t)row * N + col] = f2bf(v + extra[(size_t)row * N + col]);
                }
            }
        }
    }
    (void)M;
}

// ---------------------------------------------------------------------------
extern "C" void kernel_launch(void* const* d_in, const int* in_sizes, int n_in,
                              void* d_out, int out_size, void* d_ws, size_t ws_size,
                              hipStream_t stream)
{
    const int NB = 16384, DIN = 4096, DOUT = 4096, R = 1024;

    const float* x    = (const float*)d_in[0];
    const float* W    = (const float*)d_in[1];
    const float* bias = (const float*)d_in[2];
    const float* U    = (const float*)d_in[3];
    const float* S    = (const float*)d_in[4];
    const float* V    = (const float*)d_in[5];
    const float* th_u = (const float*)d_in[6];
    const float* th_v = (const float*)d_in[7];
    float* out = (float*)d_out;

    char* ws = (char*)d_ws;
    size_t off = 0;
    auto alloc = [&](size_t bytes) {
        char* p = ws + off;
        off += (bytes + 255) & ~(size_t)255;
        return p;
    };
    unsigned short* Xb   = (unsigned short*)alloc((size_t)NB * DIN * 2);
    unsigned short* Wctb = (unsigned short*)alloc((size_t)DOUT * DIN * 2);
    unsigned short* RVsb = (unsigned short*)alloc((size_t)R * R * 2);
    unsigned short* RUb  = (unsigned short*)alloc((size_t)R * R * 2);
    unsigned short* Tb   = (unsigned short*)alloc((size_t)R * R * 2);
    unsigned short* Ub   = (unsigned short*)alloc((size_t)DOUT * R * 2);
    unsigned short* Gb   = (unsigned short*)alloc((size_t)DOUT * R * 2);
    unsigned short* Vtb  = (unsigned short*)alloc((size_t)DIN * R * 2);
    if (off > ws_size) return;

    // 1. Butterfly rotations -> RVs (S-scaled) bf16, RU bf16
    butterfly_rows_kernel<<<2048, 256, 0, stream>>>(th_v, th_u, S, RVsb, RUb);

    // 2. Converts: x -> bf16, U -> bf16, V -> V^T bf16
    cvt_f32_bf16_x8<<<(NB * (size_t)DIN) / 2048, 256, 0, stream>>>(x, Xb);
    cvt_f32_bf16_x8<<<((size_t)DOUT * R) / 2048, 256, 0, stream>>>(U, Ub);
    transpose_to_bf16<<<dim3(DIN / 32, R / 32), 256, 0, stream>>>(V, Vtb, R, DIN);

    // 3. T[b,a] = sum_k RVs[b,k] * RU[a,k]
    gemm_nt<2><<<dim3(R / 128, R / 128), 256, 0, stream>>>(
        RVsb, RUb, nullptr, Tb, nullptr, R, R, R);

    // 4. G[o,b] = sum_a U[o,a] * T[b,a]
    gemm_nt<2><<<dim3(R / 128, DOUT / 128), 256, 0, stream>>>(
        Ub, Tb, nullptr, Gb, nullptr, DOUT, R, R);

    // 5. Wct[o,i] = W[o,i] + sum_b G[o,b] * Vt[i,b]   (256-tile, EPI3)
    gemm256<3><<<dim3(DIN / 256, DOUT / 256), 512, 0, stream>>>(
        Gb, Vtb, nullptr, Wctb, W, DOUT, DIN, R, 0);

    // 6. out[n,o] = sum_i Xb[n,i] * Wctb[o,i] + bias[o] (256-tile, EPI1, XCD swz)
    gemm256<1><<<dim3(DOUT / 256, NB / 256), 512, 0, stream>>>(
        Xb, Wctb, out, nullptr, bias, NB, DOUT, DIN, 1);
}

// Round 2
// 1141.802 us; speedup vs baseline: 1.1487x; 1.0530x over previous
//
#include <hip/hip_runtime.h>
#include <cstdint>
#include <cstddef>

// ---------------------------------------------------------------------------
// SOARALinear: out = x @ W^T + bias + x @ V^T @ R_V @ diag(S) @ R_U^T @ U^T
// Collapsed:   Wct = W + U @ (R_U diag(S) R_V^T) @ V ;  out = x @ Wct^T + bias
// Large GEMMs: 256x256 tile, BK=64, 8 waves, 8-phase-style schedule:
//   per K-tile 4 phases, each {ds_read quadrant || stage 1 half-tile ->
//   counted vmcnt -> barrier -> lgkmcnt(0) -> setprio+16 MFMA -> barrier}.
//   Waits derived from the staging queue: vmcnt(4) at phase ends 1,2,4;
//   never drains to 0 in steady state. LDS XOR-swizzled (0 bank conflicts).
// Small GEMMs keep the proven 128x128 kernel.
// ---------------------------------------------------------------------------

typedef __bf16 bf16x8 __attribute__((ext_vector_type(8)));
typedef float floatx4 __attribute__((ext_vector_type(4)));
typedef unsigned short ushortx8 __attribute__((ext_vector_type(8)));

__device__ __forceinline__ unsigned short f2bf(float f) {
    unsigned int u = __builtin_bit_cast(unsigned int, f);
    u += 0x7FFFu + ((u >> 16) & 1u);   // round-to-nearest-even
    return (unsigned short)(u >> 16);
}

__device__ __forceinline__ void gld_lds16(const void* g, void* l) {
    __builtin_amdgcn_global_load_lds(
        (const __attribute__((address_space(1))) void*)g,
        (__attribute__((address_space(3))) void*)l,
        16, 0, 0);
}

__device__ __forceinline__ bf16x8 ldsv(const char* p) {
    return __builtin_bit_cast(bf16x8, *(const ushortx8*)p);
}

#define MFMA_BF16(a, b, c) __builtin_amdgcn_mfma_f32_16x16x32_bf16((a), (b), (c), 0, 0, 0)

// ---------------------------------------------------------------------------
// Butterfly rows: R = C_0 C_1 ... C_9 (d=1024).
// mat 0 -> RVs (R_V with column k scaled by S[k]) bf16 ; mat 1 -> R_U bf16
// ---------------------------------------------------------------------------
__global__ __launch_bounds__(256) void butterfly_rows_kernel(
    const float* __restrict__ thetas_v, const float* __restrict__ thetas_u,
    const float* __restrict__ S,
    unsigned short* __restrict__ RVsb, unsigned short* __restrict__ RUb)
{
    const int d = 1024;
    __shared__ float w[1024];
    const int b   = blockIdx.x;
    const int mat = b >> 10;        // 0: V, 1: U
    const int row = b & 1023;
    const float* th = mat ? thetas_u : thetas_v;
    const int t = threadIdx.x;

    for (int i = t; i < d; i += 256) w[i] = (i == row) ? 1.f : 0.f;
    __syncthreads();

    for (int j = 0; j < 10; ++j) {
        const int sh = 9 - j;
        const int halfm1 = (1 << sh) - 1;
        for (int i = t; i < d / 2; i += 256) {
            const int blk = i >> sh;
            const int off = i & halfm1;
            const int p = (blk << (sh + 1)) + off;
            const int q = p + (halfm1 + 1);
            const float theta = th[j * (d / 2) + i];
            float s, c;
            __sincosf(theta, &s, &c);
            const float wp = w[p], wq = w[q];
            w[p] = c * wp + s * wq;
            w[q] = -s * wp + c * wq;
        }
        __syncthreads();
    }

    if (mat == 0) {
        for (int i = t; i < d; i += 256) RVsb[row * d + i] = f2bf(w[i] * S[i]);
    } else {
        for (int i = t; i < d; i += 256) RUb[row * d + i] = f2bf(w[i]);
    }
}

// ---------------------------------------------------------------------------
__global__ __launch_bounds__(256) void cvt_f32_bf16_x8(
    const float* __restrict__ src, unsigned short* __restrict__ dst)
{
    const size_t i = ((size_t)blockIdx.x * 256 + threadIdx.x) * 8;
    float4 a = *(const float4*)(src + i);
    float4 b = *(const float4*)(src + i + 4);
    ushortx8 o;
    o[0] = f2bf(a.x); o[1] = f2bf(a.y); o[2] = f2bf(a.z); o[3] = f2bf(a.w);
    o[4] = f2bf(b.x); o[5] = f2bf(b.y); o[6] = f2bf(b.z); o[7] = f2bf(b.w);
    *(ushortx8*)(dst + i) = o;
}

// ---------------------------------------------------------------------------
__global__ __launch_bounds__(256) void transpose_to_bf16(
    const float* __restrict__ src, unsigned short* __restrict__ dst,
    int rows, int cols)
{
    __shared__ float tile[32][33];
    const int tx = threadIdx.x & 31, ty = threadIdx.x >> 5;
    const int c0 = blockIdx.x * 32, r0 = blockIdx.y * 32;
    for (int i = 0; i < 32; i += 8)
        tile[ty + i][tx] = src[(size_t)(r0 + ty + i) * cols + c0 + tx];
    __syncthreads();
    for (int i = 0; i < 32; i += 8)
        dst[(size_t)(c0 + ty + i) * rows + r0 + tx] = f2bf(tile[tx][ty + i]);
}

// ---------------------------------------------------------------------------
// Small NT GEMM (the two 1024-class rotation GEMMs): 128x128 tile.
// ---------------------------------------------------------------------------
template <int EPI>
__global__ __launch_bounds__(256) void gemm_nt(
    const unsigned short* __restrict__ A,
    const unsigned short* __restrict__ B,
    float* __restrict__ Cf,
    unsigned short* __restrict__ Cb,
    const float* __restrict__ extra,
    int M, int N, int K)
{
    __shared__ __align__(16) unsigned short As[128 * 32];
    __shared__ __align__(16) unsigned short Bs[128 * 32];

    const int tid  = threadIdx.x;
    const int lane = tid & 63;
    const int wave = tid >> 6;
    const int wm = wave >> 1, wn = wave & 1;

    const int m0 = blockIdx.y * 128;
    const int n0 = blockIdx.x * 128;

    const int srow = wave * 32 + (lane >> 2);
    const int scol = (lane & 3) * 8;

    const unsigned short* gA = A + (size_t)(m0 + srow) * K + scol;
    const unsigned short* gB = B + (size_t)(n0 + srow) * K + scol;
    unsigned short* lA = As + wave * 32 * 32;
    unsigned short* lB = Bs + wave * 32 * 32;

    floatx4 acc[4][4];
#pragma unroll
    for (int i = 0; i < 4; ++i)
#pragma unroll
        for (int j = 0; j < 4; ++j) acc[i][j] = (floatx4)0.f;

    const int ar = lane & 15;
    const int ak = (lane >> 4) * 8;

    for (int kk = 0; kk < K; kk += 32) {
        gld_lds16(gA + kk, lA);
        gld_lds16(gA + kk + (size_t)16 * K, lA + 512);
        gld_lds16(gB + kk, lB);
        gld_lds16(gB + kk + (size_t)16 * K, lB + 512);
        __syncthreads();

        bf16x8 af[4], bfr[4];
#pragma unroll
        for (int tm = 0; tm < 4; ++tm)
            af[tm] = __builtin_bit_cast(bf16x8,
                *(const ushortx8*)&As[(wm * 64 + tm * 16 + ar) * 32 + ak]);
#pragma unroll
        for (int tn = 0; tn < 4; ++tn)
            bfr[tn] = __builtin_bit_cast(bf16x8,
                *(const ushortx8*)&Bs[(wn * 64 + tn * 16 + ar) * 32 + ak]);
#pragma unroll
        for (int tm = 0; tm < 4; ++tm)
#pragma unroll
            for (int tn = 0; tn < 4; ++tn)
                acc[tm][tn] = MFMA_BF16(af[tm], bfr[tn], acc[tm][tn]);
        __syncthreads();
    }

#pragma unroll
    for (int tm = 0; tm < 4; ++tm) {
#pragma unroll
        for (int tn = 0; tn < 4; ++tn) {
#pragma unroll
            for (int r = 0; r < 4; ++r) {
                const int row = m0 + wm * 64 + tm * 16 + (lane >> 4) * 4 + r;
                const int col = n0 + wn * 64 + tn * 16 + (lane & 15);
                const float v = acc[tm][tn][r];
                if (EPI == 1) {
                    Cf[(size_t)row * N + col] = v + extra[col];
                } else if (EPI == 2) {
                    Cb[(size_t)row * N + col] = f2bf(v);
                } else {
                    Cb[(size_t)row * N + col] = f2bf(v + extra[(size_t)row * N + col]);
                }
            }
        }
    }
}

// ---------------------------------------------------------------------------
// Large NT GEMM: 256x256 tile, BK=64, 512 threads (8 waves).
// LDS: As/Bs[2 dbuf][2 half][128][64] bf16, XOR-swizzled rows (linear LDS
// dest + inverse-swizzled global source + swizzled ds_read).
// Wave (wm,wn) = (wave>>2, wave&3). Per-wave output = 4 scattered 64x32
// blocks: rows {Mq*128 + wm*64 + mf*16}, cols {Nq*128 + wn*32 + nf*16} so
// quadrant (Mq,Nq) reads exactly A-half Mq and B-half Nq.
// Per K-tile 4 phases (quad order (0,0),(0,1),(1,1),(1,0)); staging one
// half-tile per phase for tile t+1 in order HA0,HB0,HB1,HA1. Queue-derived
// counted waits: vmcnt(4) at phase ends 1,2,4 (steady state), drain
// vmcnt(2)/vmcnt(0) only on the final tile.
// EPI 1: f32 out + bias[col] ;  EPI 3: bf16 out + f32 extra[M,N]
// M,N multiples of 256; K multiple of 64, K/64 >= 2.
// ---------------------------------------------------------------------------
template <int EPI>
__global__ __launch_bounds__(512, 2) void gemm256(
    const unsigned short* __restrict__ A,
    const unsigned short* __restrict__ B,
    float* __restrict__ Cf,
    unsigned short* __restrict__ Cb,
    const float* __restrict__ extra,
    int M, int N, int K, int swz_on)
{
    __shared__ __align__(16) unsigned short As[2][2][128][64];
    __shared__ __align__(16) unsigned short Bs[2][2][128][64];

    const int tid  = threadIdx.x;
    const int lane = tid & 63;
    const int wave = tid >> 6;
    const int wm = wave >> 2;      // 0..1
    const int wn = wave & 3;       // 0..3

    int bx = blockIdx.x, by = blockIdx.y;
    if (swz_on) {                  // XCD-aware bijective swizzle (nwg % 8 == 0)
        const int gx  = gridDim.x;
        const int nwg = gx * gridDim.y;
        const int f   = by * gx + bx;
        const int g   = (f & 7) * (nwg >> 3) + (f >> 3);
        bx = g % gx;
        by = g / gx;
    }
    const int m0 = by * 256;
    const int n0 = bx * 256;

    // ---- staging: linear LDS dest, inverse-swizzled global source
    const int srow  = tid >> 3;                          // 0..63 in a 64-row slab
    const int scolb = (tid & 7) << 4;                    // physical col byte
    const int scol  = (scolb ^ ((srow & 7) << 4)) >> 1;  // logical col (elems)
    const unsigned short* gA = A + (size_t)(m0 + srow) * K + scol;
    const unsigned short* gB = B + (size_t)(n0 + srow) * K + scol;
    char* lA = (char*)As + (wave << 10);                 // wave-uniform base
    char* lB = (char*)Bs + (wave << 10);
    const size_t rs64 = (size_t)64 * K;                  // 64-row stride

    auto stA = [&](int t1, int h) {                      // stage A half-tile h of K-tile t1
        const unsigned short* s = gA + (size_t)h * 2 * rs64 + (size_t)t1 * 64;
        char* l = lA + (t1 & 1) * 32768 + h * 16384;
        gld_lds16(s, l);
        gld_lds16(s + rs64, l + 8192);
    };
    auto stB = [&](int t1, int h) {
        const unsigned short* s = gB + (size_t)h * 2 * rs64 + (size_t)t1 * 64;
        char* l = lB + (t1 & 1) * 32768 + h * 16384;
        gld_lds16(s, l);
        gld_lds16(s + rs64, l + 8192);
    };

    // ---- fragment read addressing (swizzled)
    const int fr  = lane & 15;
    const int kg  = lane >> 4;                 // 0..3 -> K elems 8*kg
    const int swz = (fr & 7) << 4;
    const int ca0 = (kg << 4) ^ swz;           // K-step 0 col byte
    const int ca1 = (64 + (kg << 4)) ^ swz;    // K-step 1 col byte
    const int arb = (wm * 64 + fr) * 128;      // A byte row base within half
    const int brb = (wn * 32 + fr) * 128;      // B byte row base within half

    floatx4 acc[8][4];
#pragma unroll
    for (int i = 0; i < 8; ++i)
#pragma unroll
        for (int j = 0; j < 4; ++j) acc[i][j] = (floatx4)0.f;

    const int nkt = K >> 6;

    // prologue: stage K-tile 0 (order HA0, HB0, HB1, HA1), wait first two
    stA(0, 0); stB(0, 0); stB(0, 1); stA(0, 1);
    asm volatile("s_waitcnt vmcnt(4)" ::: "memory");
    __builtin_amdgcn_s_barrier();
    __builtin_amdgcn_sched_barrier(0);

    for (int t = 0; t < nkt; ++t) {
        const bool stg = (t + 1 < nkt);
        const char* Ad = (const char*)As + (t & 1) * 32768;
        const char* Bd = (const char*)Bs + (t & 1) * 32768;

        bf16x8 af[4][2], b0[2][2], b1[2][2];

        // ==== P1: read A-half0 + B-half0 ; stage HA0(t+1) ; quad (0,0) ====
#pragma unroll
        for (int mf = 0; mf < 4; ++mf) {
            af[mf][0] = ldsv(Ad + arb + mf * 2048 + ca0);
            af[mf][1] = ldsv(Ad + arb + mf * 2048 + ca1);
        }
#pragma unroll
        for (int nf = 0; nf < 2; ++nf) {
            b0[nf][0] = ldsv(Bd + brb + nf * 2048 + ca0);
            b0[nf][1] = ldsv(Bd + brb + nf * 2048 + ca1);
        }
        if (stg) { stA(t + 1, 0); asm volatile("s_waitcnt vmcnt(4)" ::: "memory"); }
        else     {                asm volatile("s_waitcnt vmcnt(2)" ::: "memory"); }
        __builtin_amdgcn_s_barrier();
        asm volatile("s_waitcnt lgkmcnt(0)" ::: "memory");
        __builtin_amdgcn_sched_barrier(0);
        __builtin_amdgcn_s_setprio(1);
#pragma unroll
        for (int mf = 0; mf < 4; ++mf)
#pragma unroll
            for (int nf = 0; nf < 2; ++nf) {
                acc[mf][nf] = MFMA_BF16(af[mf][0], b0[nf][0], acc[mf][nf]);
                acc[mf][nf] = MFMA_BF16(af[mf][1], b0[nf][1], acc[mf][nf]);
            }
        __builtin_amdgcn_s_setprio(0);
        __builtin_amdgcn_s_barrier();
        __builtin_amdgcn_sched_barrier(0);

        // ==== P2: read B-half1 ; stage HB0(t+1) ; quad (0,1) ====
#pragma unroll
        for (int nf = 0; nf < 2; ++nf) {
            b1[nf][0] = ldsv(Bd + 16384 + brb + nf * 2048 + ca0);
            b1[nf][1] = ldsv(Bd + 16384 + brb + nf * 2048 + ca1);
        }
        if (stg) { stB(t + 1, 0); asm volatile("s_waitcnt vmcnt(4)" ::: "memory"); }
        else     {                asm volatile("s_waitcnt vmcnt(0)" ::: "memory"); }
        __builtin_amdgcn_s_barrier();
        asm volatile("s_waitcnt lgkmcnt(0)" ::: "memory");
        __builtin_amdgcn_sched_barrier(0);
        __builtin_amdgcn_s_setprio(1);
#pragma unroll
        for (int mf = 0; mf < 4; ++mf)
#pragma unroll
            for (int nf = 0; nf < 2; ++nf) {
                acc[mf][2 + nf] = MFMA_BF16(af[mf][0], b1[nf][0], acc[mf][2 + nf]);
                acc[mf][2 + nf] = MFMA_BF16(af[mf][1], b1[nf][1], acc[mf][2 + nf]);
            }
        __builtin_amdgcn_s_setprio(0);
        __builtin_amdgcn_s_barrier();
        __builtin_amdgcn_sched_barrier(0);

        // ==== P3: read A-half1 (overwrite af) ; stage HB1(t+1) ; quad (1,1) ====
#pragma unroll
        for (int mf = 0; mf < 4; ++mf) {
            af[mf][0] = ldsv(Ad + 16384 + arb + mf * 2048 + ca0);
            af[mf][1] = ldsv(Ad + 16384 + arb + mf * 2048 + ca1);
        }
        if (stg) stB(t + 1, 1);
        asm volatile("" ::: "memory");
        __builtin_amdgcn_s_barrier();
        asm volatile("s_waitcnt lgkmcnt(0)" ::: "memory");
        __builtin_amdgcn_sched_barrier(0);
        __builtin_amdgcn_s_setprio(1);
#pragma unroll
        for (int mf = 0; mf < 4; ++mf)
#pragma unroll
            for (int nf = 0; nf < 2; ++nf) {
                acc[4 + mf][2 + nf] = MFMA_BF16(af[mf][0], b1[nf][0], acc[4 + mf][2 + nf]);
                acc[4 + mf][2 + nf] = MFMA_BF16(af[mf][1], b1[nf][1], acc[4 + mf][2 + nf]);
            }
        __builtin_amdgcn_s_setprio(0);
        __builtin_amdgcn_s_barrier();
        __builtin_amdgcn_sched_barrier(0);

        // ==== P4: no reads (b0, af live) ; stage HA1(t+1) ; quad (1,0) ====
        if (stg) { stA(t + 1, 1); asm volatile("s_waitcnt vmcnt(4)" ::: "memory"); }
        else     {                asm volatile("" ::: "memory"); }
        __builtin_amdgcn_s_barrier();
        __builtin_amdgcn_sched_barrier(0);
        __builtin_amdgcn_s_setprio(1);
#pragma unroll
        for (int mf = 0; mf < 4; ++mf)
#pragma unroll
            for (int nf = 0; nf < 2; ++nf) {
                acc[4 + mf][nf] = MFMA_BF16(af[mf][0], b0[nf][0], acc[4 + mf][nf]);
                acc[4 + mf][nf] = MFMA_BF16(af[mf][1], b0[nf][1], acc[4 + mf][nf]);
            }
        __builtin_amdgcn_s_setprio(0);
        __builtin_amdgcn_s_barrier();
        __builtin_amdgcn_sched_barrier(0);
    }

    // epilogue: C/D layout col = lane&15, row = (lane>>4)*4 + r
    const int er4 = (lane >> 4) << 2;
    const int ec  = lane & 15;
#pragma unroll
    for (int Mq = 0; Mq < 2; ++Mq)
#pragma unroll
        for (int mf = 0; mf < 4; ++mf)
#pragma unroll
            for (int Nq = 0; Nq < 2; ++Nq)
#pragma unroll
                for (int nf = 0; nf < 2; ++nf)
#pragma unroll
                    for (int r = 0; r < 4; ++r) {
                        const int row = m0 + Mq * 128 + wm * 64 + mf * 16 + er4 + r;
                        const int col = n0 + Nq * 128 + wn * 32 + nf * 16 + ec;
                        const float v = acc[Mq * 4 + mf][Nq * 2 + nf][r];
                        if (EPI == 1) {
                            Cf[(size_t)row * N + col] = v + extra[col];
                        } else {
                            Cb[(size_t)row * N + col] = f2bf(v + extra[(size_t)row * N + col]);
                        }
                    }
    (void)M;
}

// ---------------------------------------------------------------------------
extern "C" void kernel_launch(void* const* d_in, const int* in_sizes, int n_in,
                              void* d_out, int out_size, void* d_ws, size_t ws_size,
                              hipStream_t stream)
{
    const int NB = 16384, DIN = 4096, DOUT = 4096, R = 1024;

    const float* x    = (const float*)d_in[0];
    const float* W    = (const float*)d_in[1];
    const float* bias = (const float*)d_in[2];
    const float* U    = (const float*)d_in[3];
    const float* S    = (const float*)d_in[4];
    const float* V    = (const float*)d_in[5];
    const float* th_u = (const float*)d_in[6];
    const float* th_v = (const float*)d_in[7];
    float* out = (float*)d_out;

    char* ws = (char*)d_ws;
    size_t off = 0;
    auto alloc = [&](size_t bytes) {
        char* p = ws + off;
        off += (bytes + 255) & ~(size_t)255;
        return p;
    };
    unsigned short* Xb   = (unsigned short*)alloc((size_t)NB * DIN * 2);
    unsigned short* Wctb = (unsigned short*)alloc((size_t)DOUT * DIN * 2);
    unsigned short* RVsb = (unsigned short*)alloc((size_t)R * R * 2);
    unsigned short* RUb  = (unsigned short*)alloc((size_t)R * R * 2);
    unsigned short* Tb   = (unsigned short*)alloc((size_t)R * R * 2);
    unsigned short* Ub   = (unsigned short*)alloc((size_t)DOUT * R * 2);
    unsigned short* Gb   = (unsigned short*)alloc((size_t)DOUT * R * 2);
    unsigned short* Vtb  = (unsigned short*)alloc((size_t)DIN * R * 2);
    if (off > ws_size) return;

    // 1. Butterfly rotations -> RVs (S-scaled) bf16, RU bf16
    butterfly_rows_kernel<<<2048, 256, 0, stream>>>(th_v, th_u, S, RVsb, RUb);

    // 2. Converts: x -> bf16, U -> bf16, V -> V^T bf16
    cvt_f32_bf16_x8<<<(NB * (size_t)DIN) / 2048, 256, 0, stream>>>(x, Xb);
    cvt_f32_bf16_x8<<<((size_t)DOUT * R) / 2048, 256, 0, stream>>>(U, Ub);
    transpose_to_bf16<<<dim3(DIN / 32, R / 32), 256, 0, stream>>>(V, Vtb, R, DIN);

    // 3. T[b,a] = sum_k RVs[b,k] * RU[a,k]
    gemm_nt<2><<<dim3(R / 128, R / 128), 256, 0, stream>>>(
        RVsb, RUb, nullptr, Tb, nullptr, R, R, R);

    // 4. G[o,b] = sum_a U[o,a] * T[b,a]
    gemm_nt<2><<<dim3(R / 128, DOUT / 128), 256, 0, stream>>>(
        Ub, Tb, nullptr, Gb, nullptr, DOUT, R, R);

    // 5. Wct[o,i] = W[o,i] + sum_b G[o,b] * Vt[i,b]   (256-tile, EPI3)
    gemm256<3><<<dim3(DIN / 256, DOUT / 256), 512, 0, stream>>>(
        Gb, Vtb, nullptr, Wctb, W, DOUT, DIN, R, 0);

    // 6. out[n,o] = sum_i Xb[n,i] * Wctb[o,i] + bias[o] (256-tile, EPI1, XCD swz)
    gemm256<1><<<dim3(DOUT / 256, NB / 256), 512, 0, stream>>>(
        Xb, Wctb, out, nullptr, bias, NB, DOUT, DIN, 1);
}

// Round 3
// 1127.656 us; speedup vs baseline: 1.1632x; 1.0125x over previous
//
#include <hip/hip_runtime.h>
#include <cstdint>
#include <cstddef>

// ---------------------------------------------------------------------------
// SOARALinear: out = x @ W^T + bias + x @ V^T @ R_V @ diag(S) @ R_U^T @ U^T
// Collapsed:   Wct = W + U @ (R_U diag(S) R_V^T) @ V ;  out = x @ Wct^T + bias
// Large GEMMs: 256x256 tile, BK=64, 8 waves, software-pipelined fragments:
//   ds_reads issued one phase ahead of their MFMA use (counted lgkm waits by
//   the compiler), counted vmcnt(6) (3 half-tiles in flight), 3 barriers per
//   K-tile. LDS XOR-swizzled (0 bank conflicts). setprio around MFMA.
// Small GEMMs keep the proven 128x128 kernel.
// ---------------------------------------------------------------------------

typedef __bf16 bf16x8 __attribute__((ext_vector_type(8)));
typedef float floatx4 __attribute__((ext_vector_type(4)));
typedef unsigned short ushortx8 __attribute__((ext_vector_type(8)));

__device__ __forceinline__ unsigned short f2bf(float f) {
    unsigned int u = __builtin_bit_cast(unsigned int, f);
    u += 0x7FFFu + ((u >> 16) & 1u);   // round-to-nearest-even
    return (unsigned short)(u >> 16);
}

__device__ __forceinline__ void gld_lds16(const void* g, void* l) {
    __builtin_amdgcn_global_load_lds(
        (const __attribute__((address_space(1))) void*)g,
        (__attribute__((address_space(3))) void*)l,
        16, 0, 0);
}

__device__ __forceinline__ bf16x8 ldsv(const char* p) {
    return __builtin_bit_cast(bf16x8, *(const ushortx8*)p);
}

#define MFMA_BF16(a, b, c) __builtin_amdgcn_mfma_f32_16x16x32_bf16((a), (b), (c), 0, 0, 0)
#define SCHED0() __builtin_amdgcn_sched_barrier(0)

// ---------------------------------------------------------------------------
// Butterfly rows: R = C_0 C_1 ... C_9 (d=1024).
// mat 0 -> RVs (R_V with column k scaled by S[k]) bf16 ; mat 1 -> R_U bf16
// ---------------------------------------------------------------------------
__global__ __launch_bounds__(256) void butterfly_rows_kernel(
    const float* __restrict__ thetas_v, const float* __restrict__ thetas_u,
    const float* __restrict__ S,
    unsigned short* __restrict__ RVsb, unsigned short* __restrict__ RUb)
{
    const int d = 1024;
    __shared__ float w[1024];
    const int b   = blockIdx.x;
    const int mat = b >> 10;        // 0: V, 1: U
    const int row = b & 1023;
    const float* th = mat ? thetas_u : thetas_v;
    const int t = threadIdx.x;

    for (int i = t; i < d; i += 256) w[i] = (i == row) ? 1.f : 0.f;
    __syncthreads();

    for (int j = 0; j < 10; ++j) {
        const int sh = 9 - j;
        const int halfm1 = (1 << sh) - 1;
        for (int i = t; i < d / 2; i += 256) {
            const int blk = i >> sh;
            const int off = i & halfm1;
            const int p = (blk << (sh + 1)) + off;
            const int q = p + (halfm1 + 1);
            const float theta = th[j * (d / 2) + i];
            float s, c;
            __sincosf(theta, &s, &c);
            const float wp = w[p], wq = w[q];
            w[p] = c * wp + s * wq;
            w[q] = -s * wp + c * wq;
        }
        __syncthreads();
    }

    if (mat == 0) {
        for (int i = t; i < d; i += 256) RVsb[row * d + i] = f2bf(w[i] * S[i]);
    } else {
        for (int i = t; i < d; i += 256) RUb[row * d + i] = f2bf(w[i]);
    }
}

// ---------------------------------------------------------------------------
__global__ __launch_bounds__(256) void cvt_f32_bf16_x8(
    const float* __restrict__ src, unsigned short* __restrict__ dst)
{
    const size_t i = ((size_t)blockIdx.x * 256 + threadIdx.x) * 8;
    float4 a = *(const float4*)(src + i);
    float4 b = *(const float4*)(src + i + 4);
    ushortx8 o;
    o[0] = f2bf(a.x); o[1] = f2bf(a.y); o[2] = f2bf(a.z); o[3] = f2bf(a.w);
    o[4] = f2bf(b.x); o[5] = f2bf(b.y); o[6] = f2bf(b.z); o[7] = f2bf(b.w);
    *(ushortx8*)(dst + i) = o;
}

// ---------------------------------------------------------------------------
__global__ __launch_bounds__(256) void transpose_to_bf16(
    const float* __restrict__ src, unsigned short* __restrict__ dst,
    int rows, int cols)
{
    __shared__ float tile[32][33];
    const int tx = threadIdx.x & 31, ty = threadIdx.x >> 5;
    const int c0 = blockIdx.x * 32, r0 = blockIdx.y * 32;
    for (int i = 0; i < 32; i += 8)
        tile[ty + i][tx] = src[(size_t)(r0 + ty + i) * cols + c0 + tx];
    __syncthreads();
    for (int i = 0; i < 32; i += 8)
        dst[(size_t)(c0 + ty + i) * rows + r0 + tx] = f2bf(tile[tx][ty + i]);
}

// ---------------------------------------------------------------------------
// Small NT GEMM (the two 1024-class rotation GEMMs): 128x128 tile.
// ---------------------------------------------------------------------------
template <int EPI>
__global__ __launch_bounds__(256) void gemm_nt(
    const unsigned short* __restrict__ A,
    const unsigned short* __restrict__ B,
    float* __restrict__ Cf,
    unsigned short* __restrict__ Cb,
    const float* __restrict__ extra,
    int M, int N, int K)
{
    __shared__ __align__(16) unsigned short As[128 * 32];
    __shared__ __align__(16) unsigned short Bs[128 * 32];

    const int tid  = threadIdx.x;
    const int lane = tid & 63;
    const int wave = tid >> 6;
    const int wm = wave >> 1, wn = wave & 1;

    const int m0 = blockIdx.y * 128;
    const int n0 = blockIdx.x * 128;

    const int srow = wave * 32 + (lane >> 2);
    const int scol = (lane & 3) * 8;

    const unsigned short* gA = A + (size_t)(m0 + srow) * K + scol;
    const unsigned short* gB = B + (size_t)(n0 + srow) * K + scol;
    unsigned short* lA = As + wave * 32 * 32;
    unsigned short* lB = Bs + wave * 32 * 32;

    floatx4 acc[4][4];
#pragma unroll
    for (int i = 0; i < 4; ++i)
#pragma unroll
        for (int j = 0; j < 4; ++j) acc[i][j] = (floatx4)0.f;

    const int ar = lane & 15;
    const int ak = (lane >> 4) * 8;

    for (int kk = 0; kk < K; kk += 32) {
        gld_lds16(gA + kk, lA);
        gld_lds16(gA + kk + (size_t)16 * K, lA + 512);
        gld_lds16(gB + kk, lB);
        gld_lds16(gB + kk + (size_t)16 * K, lB + 512);
        __syncthreads();

        bf16x8 af[4], bfr[4];
#pragma unroll
        for (int tm = 0; tm < 4; ++tm)
            af[tm] = __builtin_bit_cast(bf16x8,
                *(const ushortx8*)&As[(wm * 64 + tm * 16 + ar) * 32 + ak]);
#pragma unroll
        for (int tn = 0; tn < 4; ++tn)
            bfr[tn] = __builtin_bit_cast(bf16x8,
                *(const ushortx8*)&Bs[(wn * 64 + tn * 16 + ar) * 32 + ak]);
#pragma unroll
        for (int tm = 0; tm < 4; ++tm)
#pragma unroll
            for (int tn = 0; tn < 4; ++tn)
                acc[tm][tn] = MFMA_BF16(af[tm], bfr[tn], acc[tm][tn]);
        __syncthreads();
    }

#pragma unroll
    for (int tm = 0; tm < 4; ++tm) {
#pragma unroll
        for (int tn = 0; tn < 4; ++tn) {
#pragma unroll
            for (int r = 0; r < 4; ++r) {
                const int row = m0 + wm * 64 + tm * 16 + (lane >> 4) * 4 + r;
                const int col = n0 + wn * 64 + tn * 16 + (lane & 15);
                const float v = acc[tm][tn][r];
                if (EPI == 1) {
                    Cf[(size_t)row * N + col] = v + extra[col];
                } else if (EPI == 2) {
                    Cb[(size_t)row * N + col] = f2bf(v);
                } else {
                    Cb[(size_t)row * N + col] = f2bf(v + extra[(size_t)row * N + col]);
                }
            }
        }
    }
}

// ---------------------------------------------------------------------------
// Large NT GEMM: 256x256 tile, BK=64, 512 threads (8 waves, 2M x 4N).
// LDS: As/Bs[2 dbuf][2 half][128][64] bf16, XOR-swizzled (linear dest +
// inverse-swizzled global source + swizzled ds_read).
// Software-pipelined phases (per K-tile t, quad order Q00,Q01,Q11,Q10):
//   P1: stage B0(t+1); vmcnt(6); bar; read b0,b1(t);  MFMA Q00 (af0 x b0)
//   P2: stage B1(t+1); vmcnt(6); bar; read af1(t);    MFMA Q01 (af0 x b1)
//   P3: stage A1(t+1);                                MFMA Q11 (af1 x b1)
//   P4: stage A0(t+2); vmcnt(6); bar; read af0(t+1);  MFMA Q10 (af1 x b0)
// Reads issued one phase before use -> LDS read BW overlaps MFMA (counted
// lgkm waits inserted by compiler; issue order pinned with sched_barrier).
// vmcnt(6) == 3 half-tiles in flight; derivation covers every read.
// EPI 1: f32 out + bias[col] ;  EPI 3: bf16 out + f32 extra[M,N]
// M,N multiples of 256; K multiple of 64, K/64 >= 2.
// ---------------------------------------------------------------------------
template <int EPI>
__global__ __launch_bounds__(512, 2) void gemm256(
    const unsigned short* __restrict__ A,
    const unsigned short* __restrict__ B,
    float* __restrict__ Cf,
    unsigned short* __restrict__ Cb,
    const float* __restrict__ extra,
    int M, int N, int K, int swz_on)
{
    __shared__ __align__(16) unsigned short As[2][2][128][64];
    __shared__ __align__(16) unsigned short Bs[2][2][128][64];

    const int tid  = threadIdx.x;
    const int lane = tid & 63;
    const int wave = tid >> 6;
    const int wm = wave >> 2;      // 0..1
    const int wn = wave & 3;       // 0..3

    int bx = blockIdx.x, by = blockIdx.y;
    if (swz_on) {                  // XCD-aware bijective swizzle (nwg % 8 == 0)
        const int gx  = gridDim.x;
        const int nwg = gx * gridDim.y;
        const int f   = by * gx + bx;
        const int g   = (f & 7) * (nwg >> 3) + (f >> 3);
        bx = g % gx;
        by = g / gx;
    }
    const int m0 = by * 256;
    const int n0 = bx * 256;

    // ---- staging: linear LDS dest, inverse-swizzled global source
    const int srow  = tid >> 3;                          // 0..63 in a 64-row slab
    const int scolb = (tid & 7) << 4;                    // physical col byte
    const int scol  = (scolb ^ ((srow & 7) << 4)) >> 1;  // logical col (elems)
    const unsigned short* gA = A + (size_t)(m0 + srow) * K + scol;
    const unsigned short* gB = B + (size_t)(n0 + srow) * K + scol;
    char* lA = (char*)As + (wave << 10);                 // wave-uniform base
    char* lB = (char*)Bs + (wave << 10);
    const size_t rs64 = (size_t)64 * K;                  // 64-row stride

    // stage half-tile h (A or B) of K-tile src_t into buffer dbuf
    auto stA = [&](int src_t, int dbuf, int h) {
        const unsigned short* s = gA + (size_t)h * 2 * rs64 + (size_t)src_t * 64;
        char* l = lA + dbuf * 32768 + h * 16384;
        gld_lds16(s, l);
        gld_lds16(s + rs64, l + 8192);
    };
    auto stB = [&](int src_t, int dbuf, int h) {
        const unsigned short* s = gB + (size_t)h * 2 * rs64 + (size_t)src_t * 64;
        char* l = lB + dbuf * 32768 + h * 16384;
        gld_lds16(s, l);
        gld_lds16(s + rs64, l + 8192);
    };

    // ---- fragment read addressing (swizzled)
    const int fr  = lane & 15;
    const int kg  = lane >> 4;                 // 0..3 -> K elems 8*kg
    const int swz = (fr & 7) << 4;
    const int ca0 = (kg << 4) ^ swz;           // K-step 0 col byte
    const int ca1 = (64 + (kg << 4)) ^ swz;    // K-step 1 col byte
    const int arb = (wm * 64 + fr) * 128;      // A byte row base within half
    const int brb = (wn * 32 + fr) * 128;      // B byte row base within half

    floatx4 acc[8][4];
#pragma unroll
    for (int i = 0; i < 8; ++i)
#pragma unroll
        for (int j = 0; j < 4; ++j) acc[i][j] = (floatx4)0.f;

    const int nkt = K >> 6;

    bf16x8 afA[4][2], afB[4][2], b0[2][2], b1[2][2];

    // ---- prologue: stage tile0 fully + A0(1); wait oldest 2 halves; read af0(0)
    stA(0, 0, 0); stB(0, 0, 0); stB(0, 0, 1); stA(0, 0, 1);
    stA(1, 1, 0);
    asm volatile("s_waitcnt vmcnt(6)" ::: "memory");   // A0(0), B0(0) landed
    SCHED0();
    __builtin_amdgcn_s_barrier();
    SCHED0();
    {
        const char* Ad = (const char*)As;              // buf 0
#pragma unroll
        for (int mf = 0; mf < 4; ++mf) {
            afA[mf][0] = ldsv(Ad + arb + mf * 2048 + ca0);
            afA[mf][1] = ldsv(Ad + arb + mf * 2048 + ca1);
        }
    }
    SCHED0();

    for (int t = 0; t < nkt; ++t) {
        const int cb = t & 1, nb = cb ^ 1;
        const char* Ad  = (const char*)As + cb * 32768;
        const char* Bd  = (const char*)Bs + cb * 32768;
        const char* Ad2 = (const char*)As + nb * 32768;
        const int t1 = (t + 1 < nkt) ? t + 1 : 0;      // clamped stage sources
        const int t2 = (t + 2 < nkt) ? t + 2 : 0;

        // ==== P1: stage B0(t+1); read b0,b1(t); MFMA Q00 ====
        stB(t1, nb, 0);
        asm volatile("s_waitcnt vmcnt(6)" ::: "memory");  // B1(t), B0(t) landed
        SCHED0();
        __builtin_amdgcn_s_barrier();
        SCHED0();
#pragma unroll
        for (int nf = 0; nf < 2; ++nf) {
            b0[nf][0] = ldsv(Bd + brb + nf * 2048 + ca0);
            b0[nf][1] = ldsv(Bd + brb + nf * 2048 + ca1);
        }
        SCHED0();
#pragma unroll
        for (int nf = 0; nf < 2; ++nf) {
            b1[nf][0] = ldsv(Bd + 16384 + brb + nf * 2048 + ca0);
            b1[nf][1] = ldsv(Bd + 16384 + brb + nf * 2048 + ca1);
        }
        SCHED0();
        __builtin_amdgcn_s_setprio(1);
#pragma unroll
        for (int mf = 0; mf < 4; ++mf)
#pragma unroll
            for (int nf = 0; nf < 2; ++nf) {
                acc[mf][nf] = MFMA_BF16(afA[mf][0], b0[nf][0], acc[mf][nf]);
                acc[mf][nf] = MFMA_BF16(afA[mf][1], b0[nf][1], acc[mf][nf]);
            }
        __builtin_amdgcn_s_setprio(0);
        SCHED0();

        // ==== P2: stage B1(t+1); read af1(t); MFMA Q01 ====
        stB(t1, nb, 1);
        asm volatile("s_waitcnt vmcnt(6)" ::: "memory");  // A1(t) landed
        SCHED0();
        __builtin_amdgcn_s_barrier();
        SCHED0();
#pragma unroll
        for (int mf = 0; mf < 4; ++mf) {
            afB[mf][0] = ldsv(Ad + 16384 + arb + mf * 2048 + ca0);
            afB[mf][1] = ldsv(Ad + 16384 + arb + mf * 2048 + ca1);
        }
        SCHED0();
        __builtin_amdgcn_s_setprio(1);
#pragma unroll
        for (int mf = 0; mf < 4; ++mf)
#pragma unroll
            for (int nf = 0; nf < 2; ++nf) {
                acc[mf][2 + nf] = MFMA_BF16(afA[mf][0], b1[nf][0], acc[mf][2 + nf]);
                acc[mf][2 + nf] = MFMA_BF16(afA[mf][1], b1[nf][1], acc[mf][2 + nf]);
            }
        __builtin_amdgcn_s_setprio(0);
        SCHED0();

        // ==== P3: stage A1(t+1); MFMA Q11 (no barrier, no vmcnt) ====
        stA(t1, nb, 1);
        SCHED0();
        __builtin_amdgcn_s_setprio(1);
#pragma unroll
        for (int mf = 0; mf < 4; ++mf)
#pragma unroll
            for (int nf = 0; nf < 2; ++nf) {
                acc[4 + mf][2 + nf] = MFMA_BF16(afB[mf][0], b1[nf][0], acc[4 + mf][2 + nf]);
                acc[4 + mf][2 + nf] = MFMA_BF16(afB[mf][1], b1[nf][1], acc[4 + mf][2 + nf]);
            }
        __builtin_amdgcn_s_setprio(0);
        SCHED0();

        // ==== P4: stage A0(t+2) -> current buf; read af0(t+1); MFMA Q10 ====
        stA(t2, cb, 0);
        asm volatile("s_waitcnt vmcnt(6)" ::: "memory");  // A0(t+1), B0(t+1) landed
        SCHED0();
        __builtin_amdgcn_s_barrier();
        SCHED0();
        if (t + 1 < nkt) {
#pragma unroll
            for (int mf = 0; mf < 4; ++mf) {
                afA[mf][0] = ldsv(Ad2 + arb + mf * 2048 + ca0);
                afA[mf][1] = ldsv(Ad2 + arb + mf * 2048 + ca1);
            }
        }
        SCHED0();
        __builtin_amdgcn_s_setprio(1);
#pragma unroll
        for (int mf = 0; mf < 4; ++mf)
#pragma unroll
            for (int nf = 0; nf < 2; ++nf) {
                acc[4 + mf][nf] = MFMA_BF16(afB[mf][0], b0[nf][0], acc[4 + mf][nf]);
                acc[4 + mf][nf] = MFMA_BF16(afB[mf][1], b0[nf][1], acc[4 + mf][nf]);
            }
        __builtin_amdgcn_s_setprio(0);
        SCHED0();
    }

    // epilogue: C/D layout col = lane&15, row = (lane>>4)*4 + r
    const int er4 = (lane >> 4) << 2;
    const int ec  = lane & 15;
#pragma unroll
    for (int Mq = 0; Mq < 2; ++Mq)
#pragma unroll
        for (int mf = 0; mf < 4; ++mf)
#pragma unroll
            for (int Nq = 0; Nq < 2; ++Nq)
#pragma unroll
                for (int nf = 0; nf < 2; ++nf)
#pragma unroll
                    for (int r = 0; r < 4; ++r) {
                        const int row = m0 + Mq * 128 + wm * 64 + mf * 16 + er4 + r;
                        const int col = n0 + Nq * 128 + wn * 32 + nf * 16 + ec;
                        const float v = acc[Mq * 4 + mf][Nq * 2 + nf][r];
                        if (EPI == 1) {
                            Cf[(size_t)row * N + col] = v + extra[col];
                        } else {
                            Cb[(size_t)row * N + col] = f2bf(v + extra[(size_t)row * N + col]);
                        }
                    }
    (void)M;
}

// ---------------------------------------------------------------------------
extern "C" void kernel_launch(void* const* d_in, const int* in_sizes, int n_in,
                              void* d_out, int out_size, void* d_ws, size_t ws_size,
                              hipStream_t stream)
{
    const int NB = 16384, DIN = 4096, DOUT = 4096, R = 1024;

    const float* x    = (const float*)d_in[0];
    const float* W    = (const float*)d_in[1];
    const float* bias = (const float*)d_in[2];
    const float* U    = (const float*)d_in[3];
    const float* S    = (const float*)d_in[4];
    const float* V    = (const float*)d_in[5];
    const float* th_u = (const float*)d_in[6];
    const float* th_v = (const float*)d_in[7];
    float* out = (float*)d_out;

    char* ws = (char*)d_ws;
    size_t off = 0;
    auto alloc = [&](size_t bytes) {
        char* p = ws + off;
        off += (bytes + 255) & ~(size_t)255;
        return p;
    };
    unsigned short* Xb   = (unsigned short*)alloc((size_t)NB * DIN * 2);
    unsigned short* Wctb = (unsigned short*)alloc((size_t)DOUT * DIN * 2);
    unsigned short* RVsb = (unsigned short*)alloc((size_t)R * R * 2);
    unsigned short* RUb  = (unsigned short*)alloc((size_t)R * R * 2);
    unsigned short* Tb   = (unsigned short*)alloc((size_t)R * R * 2);
    unsigned short* Ub   = (unsigned short*)alloc((size_t)DOUT * R * 2);
    unsigned short* Gb   = (unsigned short*)alloc((size_t)DOUT * R * 2);
    unsigned short* Vtb  = (unsigned short*)alloc((size_t)DIN * R * 2);
    if (off > ws_size) return;

    // 1. Butterfly rotations -> RVs (S-scaled) bf16, RU bf16
    butterfly_rows_kernel<<<2048, 256, 0, stream>>>(th_v, th_u, S, RVsb, RUb);

    // 2. Converts: x -> bf16, U -> bf16, V -> V^T bf16
    cvt_f32_bf16_x8<<<(NB * (size_t)DIN) / 2048, 256, 0, stream>>>(x, Xb);
    cvt_f32_bf16_x8<<<((size_t)DOUT * R) / 2048, 256, 0, stream>>>(U, Ub);
    transpose_to_bf16<<<dim3(DIN / 32, R / 32), 256, 0, stream>>>(V, Vtb, R, DIN);

    // 3. T[b,a] = sum_k RVs[b,k] * RU[a,k]
    gemm_nt<2><<<dim3(R / 128, R / 128), 256, 0, stream>>>(
        RVsb, RUb, nullptr, Tb, nullptr, R, R, R);

    // 4. G[o,b] = sum_a U[o,a] * T[b,a]
    gemm_nt<2><<<dim3(R / 128, DOUT / 128), 256, 0, stream>>>(
        Ub, Tb, nullptr, Gb, nullptr, DOUT, R, R);

    // 5. Wct[o,i] = W[o,i] + sum_b G[o,b] * Vt[i,b]   (256-tile, EPI3)
    gemm256<3><<<dim3(DIN / 256, DOUT / 256), 512, 0, stream>>>(
        Gb, Vtb, nullptr, Wctb, W, DOUT, DIN, R, 0);

    // 6. out[n,o] = sum_i Xb[n,i] * Wctb[o,i] + bias[o] (256-tile, EPI1, XCD swz)
    gemm256<1><<<dim3(DOUT / 256, NB / 256), 512, 0, stream>>>(
        Xb, Wctb, out, nullptr, bias, NB, DOUT, DIN, 1);
}